// Round 9
// baseline (58.613 us; speedup 1.0000x reference)
//
#include <hip/hip_runtime.h>
#include <hip/hip_bf16.h>

// Self-attention: b=32, s=2048, d=32, f32 in/out.
// BISECT ROUND: fused single-pass qkv (suspect) + byte-identical round-6 attn (known good).
// qkv (single pass): 2 threads/row, all 3 heads/thread; x read ONCE.
//   Q pre-scaled by log2e/sqrt(32); K row-major bf16; V fragment-order (VF).
// attn: flash-style, no-max softmax, fully in-register, 32 q-rows/wave,
//   K ring-2 dist-2, V ring-2 dist-1 (refills OTHER buffer only),
//   counted vmcnt WAITK(12)/WAITVM(16). [verified passing in round 6]
// ws: Kb 4MB | VF 4MB | Qb 4MB (prefetch tails land in the next region).

typedef __attribute__((ext_vector_type(8))) short bf16x8;
typedef __attribute__((ext_vector_type(4))) short bf16x4;
typedef __attribute__((ext_vector_type(4))) float f32x4;
typedef __attribute__((ext_vector_type(2))) unsigned int u32x2;
typedef __attribute__((ext_vector_type(4))) unsigned int u32x4;

#if __has_builtin(__builtin_amdgcn_mfma_f32_16x16x16bf16_1k)
#define MFMA_PV(a, b, c) __builtin_amdgcn_mfma_f32_16x16x16bf16_1k(a, b, c, 0, 0, 0)
#elif defined(__HIP_DEVICE_COMPILE__)
#error "no 16x16x16 bf16 mfma builtin on device"
#else
#define MFMA_PV(a, b, c) (c) /* host stub, never executed */
#endif

__device__ __forceinline__ unsigned cvt_pk_bf16(float lo, float hi) {
  unsigned r;
  asm("v_cvt_pk_bf16_f32 %0, %1, %2" : "=v"(r) : "v"(lo), "v"(hi));
  return r;
}
__device__ __forceinline__ bf16x4 as_bf16x4(u32x2 u) {
  union { u32x2 a; bf16x4 b; } c; c.a = u; return c.b;
}

// ---------------- QKV projection (fused, x read once) ----------------
// grid 512 blocks x 256 thr; 128 rows/block, 2 threads/row (half = tid>>7).
__global__ __launch_bounds__(256) void qkv_kernel(
    const float* __restrict__ x, const float* __restrict__ w,
    unsigned short* __restrict__ Qb, unsigned short* __restrict__ Kb,
    unsigned short* __restrict__ VF) {
  __shared__ float Wlds[3072];
  __shared__ unsigned short VFlds[4096]; // 8KB V repack buffer
  int tid = threadIdx.x;
  int rb = blockIdx.x;
#pragma unroll
  for (int i = 0; i < 12; ++i) Wlds[i * 256 + tid] = w[i * 256 + tid];
  __syncthreads();

  int row = rb * 128 + (tid & 127);
  int half = tid >> 7;
  const f32x4* x4 = (const f32x4*)(x + (size_t)row * 32);
  f32x4 xv[8];
#pragma unroll
  for (int j = 0; j < 8; ++j) xv[j] = x4[j];

  const float alpha = 1.4426950408889634f * 0.17677669529663687f; // log2e/sqrt(32)

#pragma unroll
  for (int h = 0; h < 3; ++h) {
    f32x4 acc[4];
#pragma unroll
    for (int j = 0; j < 4; ++j) acc[j] = (f32x4)0.0f;
#pragma unroll
    for (int d = 0; d < 32; ++d) {
      float xd = xv[d >> 2][d & 3];
      const f32x4* wr = (const f32x4*)&Wlds[h * 1024 + d * 32 + half * 16];
#pragma unroll
      for (int j = 0; j < 4; ++j) acc[j] += xd * wr[j];
    }

    if (h == 2) {
      // scatter 16 e-values into VF order inside LDS (layout verified round 6)
      int L = tid & 127;
      int kcl = L >> 6, kt = (L >> 4) & 3, g = (L >> 2) & 3, i = L & 3;
      int base = kcl * 2048 + half * 1024 + kt * 256 + g * 64 + i;
#pragma unroll
      for (int nn = 0; nn < 16; ++nn) {
        unsigned r = cvt_pk_bf16(acc[nn >> 2][nn & 3], acc[nn >> 2][nn & 3]);
        VFlds[base + nn * 4] = (unsigned short)(r & 0xffffu);
      }
      __syncthreads();
      char* dst = (char*)VF + (size_t)rb * 8192;
      const char* src = (const char*)VFlds;
#pragma unroll
      for (int m = 0; m < 4; ++m)
        *(u32x2*)(dst + tid * 8 + m * 2048) = *(const u32x2*)(src + tid * 8 + m * 2048);
    } else {
      float sc = (h == 0) ? alpha : 1.0f;
      u32x4 o4[2];
#pragma unroll
      for (int q = 0; q < 2; ++q)
#pragma unroll
        for (int c = 0; c < 4; ++c) {
          int e = q * 8 + c * 2;
          o4[q][c] = cvt_pk_bf16(acc[e >> 2][e & 3] * sc, acc[(e + 1) >> 2][(e + 1) & 3] * sc);
        }
      u32x4* dst = (u32x4*)((h == 0 ? Qb : Kb) + (size_t)row * 32 + half * 16);
      dst[0] = o4[0];
      dst[1] = o4[1];
    }
  }
}

// ---------------- Flash attention (round-6 verified structure) ----------------
#define GLOADX4(dst, ptr, OFF)                                   \
  asm volatile("global_load_dwordx4 %0, %1, off offset:" #OFF    \
               : "=v"(dst) : "v"(ptr))
#define GLOADX2(dst, ptr, OFF)                                   \
  asm volatile("global_load_dwordx2 %0, %1, off offset:" #OFF    \
               : "=v"(dst) : "v"(ptr))

#define WAITK(KS)                                                \
  asm volatile("s_waitcnt vmcnt(12)"                             \
               : "+v"(KS[0]), "+v"(KS[1]), "+v"(KS[2]), "+v"(KS[3]))
#define WAITVM(VS)                                               \
  asm volatile("s_waitcnt vmcnt(16)"                             \
               : "+v"(VS[0]), "+v"(VS[1]), "+v"(VS[2]), "+v"(VS[3]), \
                 "+v"(VS[4]), "+v"(VS[5]), "+v"(VS[6]), "+v"(VS[7]))

#define PREFK(KS) {                                              \
    GLOADX4(KS[0], kP, 0);    GLOADX4(KS[1], kP, 1024);          \
    GLOADX4(KS[2], kP, 2048); GLOADX4(KS[3], kP, 3072);          \
    kP += 4096; }

#define PREFV(VS) {                                              \
    GLOADX2(VS[0], vP, 0);    GLOADX2(VS[1], vP, 512);           \
    GLOADX2(VS[2], vP, 1024); GLOADX2(VS[3], vP, 1536);          \
    GLOADX2(VS[4], vP, 2048); GLOADX2(VS[5], vP, 2560);          \
    GLOADX2(VS[6], vP, 3072); GLOADX2(VS[7], vP, 3584);          \
    vP += 4096; }

#define SMAX(SF, PK, I2, LS) {                                   \
    float p0 = __builtin_amdgcn_exp2f(SF[0]);                    \
    float p1 = __builtin_amdgcn_exp2f(SF[1]);                    \
    float p2 = __builtin_amdgcn_exp2f(SF[2]);                    \
    float p3 = __builtin_amdgcn_exp2f(SF[3]);                    \
    LS += (p0 + p1) + (p2 + p3);                                 \
    PK[I2] = cvt_pk_bf16(p0, p1);                                \
    PK[I2 + 1] = cvt_pk_bf16(p2, p3); }

#define PVKT(KT, VS) {                                           \
    bf16x4 a0 = as_bf16x4(VS[KT]);                               \
    bf16x4 a1 = as_bf16x4(VS[4 + KT]);                           \
    u32x2 bwA; bwA[0] = pkA[2 * KT]; bwA[1] = pkA[2 * KT + 1];   \
    u32x2 bwB; bwB[0] = pkB[2 * KT]; bwB[1] = pkB[2 * KT + 1];   \
    bf16x4 bA = as_bf16x4(bwA);                                  \
    bf16x4 bB = as_bf16x4(bwB);                                  \
    oA0 = MFMA_PV(a0, bA, oA0);  oA1 = MFMA_PV(a1, bA, oA1);     \
    oB0 = MFMA_PV(a0, bB, oB0);  oB1 = MFMA_PV(a1, bB, oB1); }

#define BODY(KS, VA, VB) {                                                                \
    WAITK(KS);                                                                            \
    f32x4 sA0 = __builtin_amdgcn_mfma_f32_16x16x32_bf16(KS[0], qfA, (f32x4)0.0f, 0, 0, 0);\
    f32x4 sA1 = __builtin_amdgcn_mfma_f32_16x16x32_bf16(KS[1], qfA, (f32x4)0.0f, 0, 0, 0);\
    f32x4 sA2 = __builtin_amdgcn_mfma_f32_16x16x32_bf16(KS[2], qfA, (f32x4)0.0f, 0, 0, 0);\
    f32x4 sA3 = __builtin_amdgcn_mfma_f32_16x16x32_bf16(KS[3], qfA, (f32x4)0.0f, 0, 0, 0);\
    f32x4 sB0 = __builtin_amdgcn_mfma_f32_16x16x32_bf16(KS[0], qfB, (f32x4)0.0f, 0, 0, 0);\
    f32x4 sB1 = __builtin_amdgcn_mfma_f32_16x16x32_bf16(KS[1], qfB, (f32x4)0.0f, 0, 0, 0);\
    f32x4 sB2 = __builtin_amdgcn_mfma_f32_16x16x32_bf16(KS[2], qfB, (f32x4)0.0f, 0, 0, 0);\
    f32x4 sB3 = __builtin_amdgcn_mfma_f32_16x16x32_bf16(KS[3], qfB, (f32x4)0.0f, 0, 0, 0);\
    PREFV(VB);                                                                            \
    PREFK(KS);                                                                            \
    unsigned pkA[8], pkB[8];                                                              \
    SMAX(sA0, pkA, 0, lsumA) SMAX(sA1, pkA, 2, lsumA)                                     \
    SMAX(sA2, pkA, 4, lsumA) SMAX(sA3, pkA, 6, lsumA)                                     \
    SMAX(sB0, pkB, 0, lsumB) SMAX(sB1, pkB, 2, lsumB)                                     \
    SMAX(sB2, pkB, 4, lsumB) SMAX(sB3, pkB, 6, lsumB)                                     \
    WAITVM(VA);                                                                           \
    PVKT(0, VA) PVKT(1, VA) PVKT(2, VA) PVKT(3, VA)                                       \
  }

// grid: 512 blocks (32 b x 16 q-tiles of 128), 256 threads (4 waves x 32 q-rows)
__global__ __launch_bounds__(256, 2) void attn_kernel(
    const unsigned short* __restrict__ Qb, const unsigned short* __restrict__ Kb,
    const unsigned short* __restrict__ VF, float* __restrict__ out) {
  int tid = threadIdx.x;
  int wv = tid >> 6, lane = tid & 63;
  int n = lane & 15, g = lane >> 4;

  // XCD-aware bijective swizzle (512 % 8 == 0): 4 batches per XCD
  int bid = blockIdx.x;
  int swz = (bid & 7) * 64 + (bid >> 3);
  int bi = swz >> 4, qt = swz & 15;

  size_t Rq = (size_t)bi * 2048 + qt * 128 + wv * 32;

  const char* qP = (const char*)(Qb + (Rq + n) * 32 + g * 8);
  const char* kP = (const char*)(Kb + (size_t)bi * 65536 + n * 32 + g * 8);
  const char* vP = (const char*)VF + (size_t)bi * 131072 + lane * 8;

  bf16x8 qfA, qfB;
  bf16x8 k0[4], k1[4];
  u32x2 v0[8], v1[8];

  f32x4 oA0 = (f32x4)0.0f, oA1 = (f32x4)0.0f; // q-rows Rq..Rq+15, eblk 0/1
  f32x4 oB0 = (f32x4)0.0f, oB1 = (f32x4)0.0f; // q-rows Rq+16..Rq+31
  float lsumA = 0.0f, lsumB = 0.0f;

  // prologue issue order: qfA,qfB, K0,V0,K1  [vmcnt math relies on this]
  GLOADX4(qfA, qP, 0);
  GLOADX4(qfB, qP, 1024);
  PREFK(k0);
  PREFV(v0);
  PREFK(k1);

  for (int t = 0; t < 16; ++t) {
    BODY(k0, v0, v1);  // body 2t
    BODY(k1, v1, v0);  // body 2t+1
  }
  // tail prefetches over-read ~8KB into the next ws region: harmless.

  // row-sums: g-groups hold disjoint t-subsets of q-row n
  lsumA += __shfl_xor(lsumA, 16);
  lsumA += __shfl_xor(lsumA, 32);
  lsumB += __shfl_xor(lsumB, 16);
  lsumB += __shfl_xor(lsumB, 32);
  float invA = 1.0f / lsumA, invB = 1.0f / lsumB;

  // O: lane(n,g) reg r holds O[q][e = eblk*16 + g*4 + r]
  float* obA = out + (Rq + n) * 32 + g * 4;
  float* obB = obA + 16 * 32;
  *(f32x4*)(obA)      = oA0 * invA;
  *(f32x4*)(obA + 16) = oA1 * invA;
  *(f32x4*)(obB)      = oB0 * invB;
  *(f32x4*)(obB + 16) = oB1 * invB;
}

extern "C" void kernel_launch(void* const* d_in, const int* in_sizes, int n_in,
                              void* d_out, int out_size, void* d_ws, size_t ws_size,
                              hipStream_t stream) {
  const float* x = (const float*)d_in[0];
  const float* w = (const float*)d_in[1];
  float* out = (float*)d_out;

  // Kb | VF | Qb: attn prefetch tails over-read a few KB past K/V regions.
  unsigned short* Kb = (unsigned short*)d_ws;          // 4MB
  unsigned short* VF = Kb + (size_t)65536 * 32;        // 4MB, fragment-order V
  unsigned short* Qb = VF + (size_t)65536 * 32;        // 4MB

  qkv_kernel<<<512, 256, 0, stream>>>(x, w, Qb, Kb, VF);
  attn_kernel<<<512, 256, 0, stream>>>(Qb, Kb, VF, out);
}

// Round 12
// 48.979 us; speedup vs baseline: 1.1967x; 1.1967x over previous
//
#include <hip/hip_runtime.h>
#include <hip/hip_bf16.h>

// Self-attention: b=32, s=2048, d=32, f32 in/out.
// qkv (split, 3-head grid): Q pre-scaled by log2e/sqrt(32);
//   K repacked to FRAGMENT order (KF); V repacked to fragment order (VF).
// attn: flash-style, no-max softmax, 16 q-rows/wave, 1024 blocks, 4 blocks/CU.
//   Block-shared K/V staged to LDS via REG-STAGING (global->VGPR->ds_write),
//   double-buffered, plain __syncthreads() only (no counted vmcnt, no raw
//   barriers, no global_load_lds). All LDS reads linear/conflict-free.
// ws: KF 4MB | VF 4MB | Qb 4MB.

typedef __attribute__((ext_vector_type(8))) short bf16x8;
typedef __attribute__((ext_vector_type(4))) short bf16x4;
typedef __attribute__((ext_vector_type(4))) float f32x4;
typedef __attribute__((ext_vector_type(2))) unsigned int u32x2;
typedef __attribute__((ext_vector_type(4))) unsigned int u32x4;

#if __has_builtin(__builtin_amdgcn_mfma_f32_16x16x16bf16_1k)
#define MFMA_PV(a, b, c) __builtin_amdgcn_mfma_f32_16x16x16bf16_1k(a, b, c, 0, 0, 0)
#elif defined(__HIP_DEVICE_COMPILE__)
#error "no 16x16x16 bf16 mfma builtin on device"
#else
#define MFMA_PV(a, b, c) (c) /* host stub, never executed */
#endif

__device__ __forceinline__ unsigned cvt_pk_bf16(float lo, float hi) {
  unsigned r;
  asm("v_cvt_pk_bf16_f32 %0, %1, %2" : "=v"(r) : "v"(lo), "v"(hi));
  return r;
}
__device__ __forceinline__ bf16x4 as_bf16x4(u32x2 u) {
  union { u32x2 a; bf16x4 b; } c; c.a = u; return c.b;
}

// ---------------- QKV projection (split; K & V fragment-order repack) ----------------
// grid 1536 = 3 heads x 512 blocks; 256 thr; half = tid>>7, 128 rows/block
__global__ __launch_bounds__(256) void qkv_kernel(
    const float* __restrict__ x, const float* __restrict__ w,
    unsigned short* __restrict__ Qb, unsigned short* __restrict__ KF,
    unsigned short* __restrict__ VF) {
  __shared__ float Wlds[1024];
  __shared__ __align__(16) unsigned char RP[8192]; // repack buffer (h==1 / h==2)
  int tid = threadIdx.x;
  int h = blockIdx.x >> 9;
  int rb = blockIdx.x & 511;
#pragma unroll
  for (int i = 0; i < 4; ++i) Wlds[i * 256 + tid] = w[h * 1024 + i * 256 + tid];
  __syncthreads();

  int row = rb * 128 + (tid & 127);
  int half = tid >> 7;
  const f32x4* x4 = (const f32x4*)(x + (size_t)row * 32);
  f32x4 xv[8];
#pragma unroll
  for (int j = 0; j < 8; ++j) xv[j] = x4[j];

  f32x4 acc[4];
#pragma unroll
  for (int j = 0; j < 4; ++j) acc[j] = (f32x4)0.0f;
#pragma unroll
  for (int d = 0; d < 32; ++d) {
    float xd = xv[d >> 2][d & 3];
    const f32x4* wr = (const f32x4*)&Wlds[d * 32 + half * 16];
#pragma unroll
    for (int j = 0; j < 4; ++j) acc[j] += xd * wr[j];
  }

  const float alpha = 1.4426950408889634f * 0.17677669529663687f; // log2e/sqrt(32)
  int L = tid & 127;

  if (h == 0) {
    u32x4 o4[2];
#pragma unroll
    for (int q = 0; q < 2; ++q)
#pragma unroll
      for (int c = 0; c < 4; ++c) {
        int e = q * 8 + c * 2;
        o4[q][c] = cvt_pk_bf16(acc[e >> 2][e & 3] * alpha, acc[(e + 1) >> 2][(e + 1) & 3] * alpha);
      }
    u32x4* dst = (u32x4*)(Qb + (size_t)row * 32 + half * 16);
    dst[0] = o4[0];
    dst[1] = o4[1];
  } else if (h == 1) {
    // K fragment-order: tile byte = kt*1024 + g*256 + n*16 (+ kcl*4096)
    int kcl = L >> 6, kt = (L >> 4) & 3, n = L & 15;
    u32x4 o4[2];
#pragma unroll
    for (int q = 0; q < 2; ++q)
#pragma unroll
      for (int c = 0; c < 4; ++c) {
        int e = q * 8 + c * 2;
        o4[q][c] = cvt_pk_bf16(acc[e >> 2][e & 3], acc[(e + 1) >> 2][(e + 1) & 3]);
      }
    // o4[j] = cols [half*16 + j*8, +8) -> g = 2*half + j
    *(u32x4*)(RP + kcl * 4096 + kt * 1024 + (2 * half + 0) * 256 + n * 16) = o4[0];
    *(u32x4*)(RP + kcl * 4096 + kt * 1024 + (2 * half + 1) * 256 + n * 16) = o4[1];
    __syncthreads();
    char* dst = (char*)KF + (size_t)rb * 8192;
#pragma unroll
    for (int m = 0; m < 4; ++m)
      *(u32x2*)(dst + tid * 8 + m * 2048) = *(const u32x2*)(RP + tid * 8 + m * 2048);
  } else {
    // V fragment-order repack (verified rounds 6/9)
    unsigned short* VFlds = (unsigned short*)RP;
    int kcl = L >> 6, kt = (L >> 4) & 3, g = (L >> 2) & 3, i = L & 3;
    int base = kcl * 2048 + half * 1024 + kt * 256 + g * 64 + i;
#pragma unroll
    for (int nn = 0; nn < 16; ++nn) {
      unsigned r = cvt_pk_bf16(acc[nn >> 2][nn & 3], acc[nn >> 2][nn & 3]);
      VFlds[base + nn * 4] = (unsigned short)(r & 0xffffu);
    }
    __syncthreads();
    char* dst = (char*)VF + (size_t)rb * 8192;
#pragma unroll
    for (int m = 0; m < 4; ++m)
      *(u32x2*)(dst + tid * 8 + m * 2048) = *(const u32x2*)(RP + tid * 8 + m * 2048);
  }
}

// ---------------- Flash attention (reg-staged LDS, compiler-managed sync) ----------------
#define SMAX(SF, I2) {                                           \
    float p0 = __builtin_amdgcn_exp2f(SF[0]);                    \
    float p1 = __builtin_amdgcn_exp2f(SF[1]);                    \
    float p2 = __builtin_amdgcn_exp2f(SF[2]);                    \
    float p3 = __builtin_amdgcn_exp2f(SF[3]);                    \
    lsum += (p0 + p1) + (p2 + p3);                               \
    pk[I2] = cvt_pk_bf16(p0, p1);                                \
    pk[I2 + 1] = cvt_pk_bf16(p2, p3); }

#define PVKT(KT, V0, V1, ACC0, ACC1) {                           \
    u32x2 bw; bw[0] = pk[2 * KT]; bw[1] = pk[2 * KT + 1];        \
    bf16x4 bb = as_bf16x4(bw);                                   \
    ACC0 = MFMA_PV(as_bf16x4(V0), bb, ACC0);                     \
    ACC1 = MFMA_PV(as_bf16x4(V1), bb, ACC1); }

// grid: 1024 blocks (32 b x 32 q-tiles of 64), 256 threads (4 waves x 16 q-rows)
__global__ __launch_bounds__(256, 4) void attn_kernel(
    const unsigned short* __restrict__ Qb, const unsigned short* __restrict__ KF,
    const unsigned short* __restrict__ VF, float* __restrict__ out) {
  __shared__ __align__(16) unsigned char lds[2][8192]; // 2 x (K 4KB | V 4KB)
  unsigned char* ldsb = &lds[0][0];
  int tid = threadIdx.x;
  int wv = tid >> 6, lane = tid & 63;
  int n = lane & 15, g = lane >> 4;

  // XCD-aware bijective swizzle (1024 % 8 == 0)
  int bid = blockIdx.x;
  int swz = (bid & 7) * 128 + (bid >> 3);
  int bi = swz >> 5, qt = swz & 31;

  size_t Rq = (size_t)bi * 2048 + qt * 64 + wv * 16;

  const unsigned char* Kg = (const unsigned char*)KF + (size_t)bi * 131072;
  const unsigned char* Vg = (const unsigned char*)VF + (size_t)bi * 131072;

  // staging: wave wv covers 2KB of the 8KB (K|V) tile; 2 x 16B per lane
  const unsigned char* sgp = (wv < 2 ? Kg : Vg) + (wv & 1) * 2048 + lane * 16;
  unsigned char* ldsw = ldsb + (wv < 2 ? 0 : 4096) + (wv & 1) * 2048 + lane * 16;

  bf16x8 qf = *(const bf16x8*)(Qb + (Rq + n) * 32 + g * 8);

  f32x4 oA0 = (f32x4)0.0f, oA1 = (f32x4)0.0f; // kt 0,1 x eblk 0,1
  f32x4 oB0 = (f32x4)0.0f, oB1 = (f32x4)0.0f; // kt 2,3 x eblk 0,1
  float lsum = 0.0f;

  bf16x8 kr0, kr1;

  // prologue: stage tile 0 into buf0
  kr0 = *(const bf16x8*)(sgp);
  kr1 = *(const bf16x8*)(sgp + 1024);
  sgp += 4096;
  *(bf16x8*)(ldsw) = kr0;
  *(bf16x8*)(ldsw + 1024) = kr1;
  __syncthreads();

  for (int t = 0; t < 32; ++t) {
    int buf = t & 1;
    if (t < 31) { // issue next tile's loads early (one compute phase of cover)
      kr0 = *(const bf16x8*)(sgp);
      kr1 = *(const bf16x8*)(sgp + 1024);
      sgp += 4096;
    }
    const unsigned char* Lp = ldsb + buf * 8192;
    bf16x8 kf0 = *(const bf16x8*)(Lp + lane * 16);
    bf16x8 kf1 = *(const bf16x8*)(Lp + lane * 16 + 1024);
    bf16x8 kf2 = *(const bf16x8*)(Lp + lane * 16 + 2048);
    bf16x8 kf3 = *(const bf16x8*)(Lp + lane * 16 + 3072);
    u32x2 vf0 = *(const u32x2*)(Lp + 4096 + lane * 8);
    u32x2 vf1 = *(const u32x2*)(Lp + 4096 + lane * 8 + 512);
    u32x2 vf2 = *(const u32x2*)(Lp + 4096 + lane * 8 + 1024);
    u32x2 vf3 = *(const u32x2*)(Lp + 4096 + lane * 8 + 1536);
    u32x2 vf4 = *(const u32x2*)(Lp + 4096 + lane * 8 + 2048);
    u32x2 vf5 = *(const u32x2*)(Lp + 4096 + lane * 8 + 2560);
    u32x2 vf6 = *(const u32x2*)(Lp + 4096 + lane * 8 + 3072);
    u32x2 vf7 = *(const u32x2*)(Lp + 4096 + lane * 8 + 3584);
    f32x4 s0 = __builtin_amdgcn_mfma_f32_16x16x32_bf16(kf0, qf, (f32x4)0.0f, 0, 0, 0);
    f32x4 s1 = __builtin_amdgcn_mfma_f32_16x16x32_bf16(kf1, qf, (f32x4)0.0f, 0, 0, 0);
    f32x4 s2 = __builtin_amdgcn_mfma_f32_16x16x32_bf16(kf2, qf, (f32x4)0.0f, 0, 0, 0);
    f32x4 s3 = __builtin_amdgcn_mfma_f32_16x16x32_bf16(kf3, qf, (f32x4)0.0f, 0, 0, 0);
    unsigned pk[8];
    SMAX(s0, 0) SMAX(s1, 2) SMAX(s2, 4) SMAX(s3, 6)
    PVKT(0, vf0, vf4, oA0, oA1) PVKT(1, vf1, vf5, oA0, oA1)
    PVKT(2, vf2, vf6, oB0, oB1) PVKT(3, vf3, vf7, oB0, oB1)
    __syncthreads();              // all waves done reading buf
    if (t < 31) {
      unsigned char* Wp = ldsw + (buf ^ 1) * 8192;
      *(bf16x8*)(Wp) = kr0;       // compiler inserts vmcnt wait before ds_write
      *(bf16x8*)(Wp + 1024) = kr1;
      __syncthreads();            // stage of tile t+1 visible to all
    }
  }

  // full row-sum for q-row n: partials live in lanes n, n+16, n+32, n+48
  lsum += __shfl_xor(lsum, 16);
  lsum += __shfl_xor(lsum, 32);
  float inv = 1.0f / lsum;

  // O: lane(n,g) reg r holds O[q=Rq+n][e = eblk*16 + g*4 + r]
  f32x4 r0 = (oA0 + oB0) * inv;
  f32x4 r1 = (oA1 + oB1) * inv;
  float* ob = out + (Rq + n) * 32 + g * 4;
  *(f32x4*)(ob)      = r0;
  *(f32x4*)(ob + 16) = r1;
}

extern "C" void kernel_launch(void* const* d_in, const int* in_sizes, int n_in,
                              void* d_out, int out_size, void* d_ws, size_t ws_size,
                              hipStream_t stream) {
  const float* x = (const float*)d_in[0];
  const float* w = (const float*)d_in[1];
  float* out = (float*)d_out;

  unsigned short* KF = (unsigned short*)d_ws;          // 4MB, fragment-order K
  unsigned short* VF = KF + (size_t)65536 * 32;        // 4MB, fragment-order V
  unsigned short* Qb = VF + (size_t)65536 * 32;        // 4MB

  qkv_kernel<<<1536, 256, 0, stream>>>(x, w, Qb, KF, VF);
  attn_kernel<<<1024, 256, 0, stream>>>(Qb, KF, VF, out);
}